// Round 22
// baseline (26.258 us; speedup 1.0000x reference)
//
#include <hip/hip_runtime.h>

// TransformerBlockQuantum: B=16384, S=8, E=8, H=8 (dk=1), NW=8, FFN=512.
// R22 = R21 pipeline (full-MFMA front, verified correct) re-shaped for
// occupancy: block = 256 thr = 4 waves = 64 tokens; grid = 2048 blocks;
// launch_bounds(256,4) -> VGPR<=128, 4 blocks/CU (LDS 35KB x4 = 140KB fits)
// = 16 waves/CU = 4 waves/SIMD (2x all prior rounds).
// Wave = 16 tokens = one 16x16 tile chain:
//   QKV 3 MFMAs -> attn (kv-pack, (j<<5)|0x18 gather) -> out_proj MFMA ->
//   ring (xor-16) -> combine x2 MFMAs -> LN1 -> zf -> 32-iter MFMA FFN ->
//   LN2 -> store. All inter-matmul data packs IN-PLACE (D layout == next B).

typedef __fp16 half2v __attribute__((ext_vector_type(2)));
typedef __fp16 half4  __attribute__((ext_vector_type(4)));
typedef float  float4v __attribute__((ext_vector_type(4)));

#define SWZ16(v) __int_as_float(__builtin_amdgcn_ds_swizzle(__float_as_int(v), (16 << 10) | 0x1F))
#define SWZI_(v, dlit) __builtin_amdgcn_ds_swizzle((v), ((dlit) << 5) | 0x18)
#define GATHERJ8(dst, src)                                  \
    do {                                                    \
        dst[0] = SWZI_(src, 0); dst[1] = SWZI_(src, 1);     \
        dst[2] = SWZI_(src, 2); dst[3] = SWZI_(src, 3);     \
        dst[4] = SWZI_(src, 4); dst[5] = SWZI_(src, 5);     \
        dst[6] = SWZI_(src, 6); dst[7] = SWZI_(src, 7);     \
    } while (0)

// wl float offsets (16-float slots, zero-padded)
#define O_RXA 0
#define O_G1  16
#define O_B1  32
#define O_RXF 48
#define O_L2B 64
#define O_G2  80
#define O_B2  96

__global__ __launch_bounds__(256, 4) void tbq_fused(
    const float* __restrict__ x,
    const float* __restrict__ ipw, const float* __restrict__ ipb,
    const float* __restrict__ opw, const float* __restrict__ opb,
    const float* __restrict__ rxa,
    const float* __restrict__ cw,  const float* __restrict__ cb,
    const float* __restrict__ g1,  const float* __restrict__ b1,
    const float* __restrict__ rxf,
    const float* __restrict__ l1w, const float* __restrict__ l1b,
    const float* __restrict__ l2w, const float* __restrict__ l2b,
    const float* __restrict__ g2,  const float* __restrict__ b2,
    float* __restrict__ out)
{
    __shared__ half4 a1l[2048];                 // 16KB FFN lin1 frags
    __shared__ half4 a2l[2048];                 // 16KB FFN lin2 frags
    __shared__ half4 frontA[320];               // 2.5KB Wq,Wk,Wv,Wo,Wc frags
    __shared__ __align__(16) float wl[112];     // params, 16-float slots

    const int tid = threadIdx.x;
    const int l   = tid & 63;
    const int wv  = tid >> 6;                   // 0..3
    const int n   = l & 15;                     // token in tile
    const int g   = l >> 4;                     // row group (0..3)
    const int k0  = g * 4;
    const int gtok = blockIdx.x * 64 + wv * 16;

    // ---- x load early (B-operand source: x^T) ----
    float4 xw = make_float4(0.f, 0.f, 0.f, 0.f);
    if (g < 2) xw = *reinterpret_cast<const float4*>(x + (gtok + n) * 8 + k0);

    const half4 zh = {(__fp16)0.f, (__fp16)0.f, (__fp16)0.f, (__fp16)0.f};

    // ---- pack: front A-frags (bias at k==8), params, FFN frags ----
    #pragma unroll 1
    for (int u0 = tid; u0 < 320; u0 += 256) {
        const int t = u0 >> 6, ll = u0 & 63;
        const int m = ll & 15, kk0 = (ll >> 4) * 4;
        half4 r = zh;
        if (m < 8) {
            const float* Wp = (t == 0) ? ipw : (t == 1) ? ipw + 64 :
                              (t == 2) ? ipw + 128 : (t == 3) ? opw : cw;
            const float* Bp = (t == 0) ? ipb : (t == 1) ? ipb + 8 :
                              (t == 2) ? ipb + 16 : (t == 3) ? opb : cb;
            #pragma unroll
            for (int j = 0; j < 4; ++j) {
                int k = kk0 + j;
                float v = (k < 8) ? Wp[m * 8 + k] : ((k == 8) ? Bp[m] : 0.f);
                r[j] = (__fp16)v;
            }
        }
        frontA[u0] = r;
    }
    if (tid < 112) {
        const int p = tid >> 4, i = tid & 15;
        float v = 0.f;
        if (i < 8) {
            v = (p == 0) ? rxa[i] : (p == 1) ? g1[i] : (p == 2) ? b1[i] :
                (p == 3) ? rxf[i] : (p == 4) ? l2b[i] : (p == 5) ? g2[i] : b2[i];
        }
        wl[p * 16 + i] = v;
    }
    #pragma unroll 1
    for (int i = 0; i < 8; ++i) {
        const int u  = tid + i * 256;
        const int nf = u >> 6, ll = u & 63;
        const int mm = ll & 15, kk0 = (ll >> 4) * 4;
        half4 r1 = zh;
        if (ll < 32) {
            float4 w = *reinterpret_cast<const float4*>(l1w + (nf * 16 + mm) * 8 + kk0);
            half2v c0 = __builtin_amdgcn_cvt_pkrtz(w.x, w.y);
            half2v c1 = __builtin_amdgcn_cvt_pkrtz(w.z, w.w);
            r1.x = c0.x; r1.y = c0.y; r1.z = c1.x; r1.w = c1.y;
        } else if (ll < 48) {
            r1.x = (__fp16)l1b[nf * 16 + mm];
        }
        a1l[u] = r1;
        half4 r2 = zh;
        if (mm < 8) {
            float4 w = *reinterpret_cast<const float4*>(l2w + mm * 512 + nf * 16 + kk0);
            half2v c0 = __builtin_amdgcn_cvt_pkrtz(w.x, w.y);
            half2v c1 = __builtin_amdgcn_cvt_pkrtz(w.z, w.w);
            r2.x = c0.x; r2.y = c0.y; r2.z = c1.x; r2.w = c1.y;
        }
        a2l[u] = r2;
    }
    __syncthreads();

    // ---- B-fragment of x (k=embed, n=token); bias row k==8 = 1 ----
    half4 bx = zh;
    if (g < 2) {
        half2v p0 = __builtin_amdgcn_cvt_pkrtz(xw.x, xw.y);
        half2v p1 = __builtin_amdgcn_cvt_pkrtz(xw.z, xw.w);
        bx.x = p0.x; bx.y = p0.y; bx.z = p1.x; bx.w = p1.y;
    } else if (g == 2) bx.x = (__fp16)1.f;

    half4 Aq = frontA[l],       Ak = frontA[64 + l], Av = frontA[128 + l];
    half4 Ao = frontA[192 + l], Ac = frontA[256 + l];

    const float4v zero4 = {0.f, 0.f, 0.f, 0.f};
    float4v qf = __builtin_amdgcn_mfma_f32_16x16x16f16(Aq, bx, zero4, 0, 0, 0);
    float4v kf = __builtin_amdgcn_mfma_f32_16x16x16f16(Ak, bx, zero4, 0, 0, 0);
    float4v vf = __builtin_amdgcn_mfma_f32_16x16x16f16(Av, bx, zero4, 0, 0, 0);

    // ---- attention: lane holds heads 4g+r of token n; j-gather in batch ----
    float orow[4];
    #pragma unroll
    for (int r = 0; r < 4; ++r) {
        half2v pk = __builtin_amdgcn_cvt_pkrtz(kf[r], vf[r]);
        int kvp = __builtin_bit_cast(int, pk);
        int kvg[8];
        GATHERJ8(kvg, kvp);
        const float qh2 = qf[r] * 1.44269504f;
        float sum = 0.f, ov = 0.f;
        #pragma unroll
        for (int j = 0; j < 8; ++j) {
            half2v kv = __builtin_bit_cast(half2v, kvg[j]);
            float p = exp2f(qh2 * (float)kv.x);
            sum += p;
            ov = fmaf(p, (float)kv.y, ov);
        }
        orow[r] = ov * __builtin_amdgcn_rcpf(sum);
    }

    // ---- out_proj: orow packs IN-PLACE to B ----
    half4 bo = zh;
    if (g < 2) {
        half2v p0 = __builtin_amdgcn_cvt_pkrtz(orow[0], orow[1]);
        half2v p1 = __builtin_amdgcn_cvt_pkrtz(orow[2], orow[3]);
        bo.x = p0.x; bo.y = p0.y; bo.z = p1.x; bo.w = p1.y;
    } else if (g == 2) bo.x = (__fp16)1.f;
    float4v aof = __builtin_amdgcn_mfma_f32_16x16x16f16(Ao, bo, zero4, 0, 0, 0);

    // ---- quantum ring: c on own 4 wires, xor-16 exchange, full z ----
    const float4 rxa4 = *reinterpret_cast<const float4*>(&wl[O_RXA + k0]);
    float cx0 = __cosf(aof[0] + rxa4.x), cx1 = __cosf(aof[1] + rxa4.y);
    float cx2 = __cosf(aof[2] + rxa4.z), cx3 = __cosf(aof[3] + rxa4.w);
    float ct0 = SWZ16(cx0), ct1 = SWZ16(cx1), ct2 = SWZ16(cx2), ct3 = SWZ16(cx3);
    const bool sel = (g == 0);
    float cc[8];
    cc[0] = sel ? cx0 : ct0; cc[1] = sel ? cx1 : ct1;
    cc[2] = sel ? cx2 : ct2; cc[3] = sel ? cx3 : ct3;
    cc[4] = sel ? ct0 : cx0; cc[5] = sel ? ct1 : cx1;
    cc[6] = sel ? ct2 : cx2; cc[7] = sel ? ct3 : cx3;
    float z8[8];
    {
        float run = cc[0];
        #pragma unroll
        for (int w = 1; w < 8; ++w) { run *= cc[w]; z8[w] = run; }
        float s17 = cc[1];
        #pragma unroll
        for (int w = 2; w < 8; ++w) s17 *= cc[w];
        z8[0] = s17;
    }

    // ---- combine1: z packs in-place (g picks own half) ----
    float zs0 = sel ? z8[0] : z8[4], zs1 = sel ? z8[1] : z8[5];
    float zs2 = sel ? z8[2] : z8[6], zs3 = sel ? z8[3] : z8[7];
    half4 bz1 = zh;
    if (g < 2) {
        half2v p0 = __builtin_amdgcn_cvt_pkrtz(zs0, zs1);
        half2v p1 = __builtin_amdgcn_cvt_pkrtz(zs2, zs3);
        bz1.x = p0.x; bz1.y = p0.y; bz1.z = p1.x; bz1.w = p1.y;
    } else if (g == 2) bz1.x = (__fp16)1.f;
    float4v qo = __builtin_amdgcn_mfma_f32_16x16x16f16(Ac, bz1, zero4, 0, 0, 0);
    float4v saqf = aof + qo;

    // ---- combine2: saq packs in-place ----
    half4 bs = zh;
    if (g < 2) {
        half2v p0 = __builtin_amdgcn_cvt_pkrtz(saqf[0], saqf[1]);
        half2v p1 = __builtin_amdgcn_cvt_pkrtz(saqf[2], saqf[3]);
        bs.x = p0.x; bs.y = p0.y; bs.z = p1.x; bs.w = p1.y;
    } else if (g == 2) bs.x = (__fp16)1.f;
    float4v atf = __builtin_amdgcn_mfma_f32_16x16x16f16(Ac, bs, zero4, 0, 0, 0);

    // ---- LayerNorm1 (xor-16 reductions across g=0/1) ----
    float r10 = xw.x + atf[0], r11 = xw.y + atf[1];
    float r12 = xw.z + atf[2], r13 = xw.w + atf[3];
    float s4 = (r10 + r11) + (r12 + r13);
    float mean = (s4 + SWZ16(s4)) * 0.125f;
    float dv0 = r10 - mean, dv1 = r11 - mean, dv2 = r12 - mean, dv3 = r13 - mean;
    float vq = (dv0 * dv0 + dv1 * dv1) + (dv2 * dv2 + dv3 * dv3);
    float var = (vq + SWZ16(vq)) * 0.125f;
    float rs = __builtin_amdgcn_rsqf(var + 1e-5f);
    const float4 g14 = *reinterpret_cast<const float4*>(&wl[O_G1 + k0]);
    const float4 b14 = *reinterpret_cast<const float4*>(&wl[O_B1 + k0]);
    float hh0 = fmaf(dv0 * rs, g14.x, b14.x);
    float hh1 = fmaf(dv1 * rs, g14.y, b14.y);
    float hh2 = fmaf(dv2 * rs, g14.z, b14.z);
    float hh3 = fmaf(dv3 * rs, g14.w, b14.w);

    // ---- zf packs in-place into FFN B-fragment ----
    const float4 rxf4 = *reinterpret_cast<const float4*>(&wl[O_RXF + k0]);
    half4 bz = zh;
    if (g < 2) {
        half2v p0 = __builtin_amdgcn_cvt_pkrtz(__cosf(hh0 + rxf4.x), __cosf(hh1 + rxf4.y));
        half2v p1 = __builtin_amdgcn_cvt_pkrtz(__cosf(hh2 + rxf4.z), __cosf(hh3 + rxf4.w));
        bz.x = p0.x; bz.y = p0.y; bz.z = p1.x; bz.w = p1.y;
    } else if (g == 2) bz.x = (__fp16)1.f;

    // ---- FFN: one tile, 32 chunks ----
    float4v acc = zero4;
    #pragma unroll 4
    for (int nf = 0; nf < 32; ++nf) {
        half4 a1f = a1l[nf * 64 + l];
        half4 a2f = a2l[nf * 64 + l];
        float4v d = __builtin_amdgcn_mfma_f32_16x16x16f16(a1f, bz, zero4, 0, 0, 0);
        half2v p0 = __builtin_amdgcn_cvt_pkrtz(d[0], d[1]);
        half2v p1 = __builtin_amdgcn_cvt_pkrtz(d[2], d[3]);
        half4 bu; bu.x = p0.x; bu.y = p0.y; bu.z = p1.x; bu.w = p1.y;
        bu = __builtin_elementwise_max(bu, zh);
        acc = __builtin_amdgcn_mfma_f32_16x16x16f16(a2f, bu, acc, 0, 0, 0);
    }

    // ---- residual + LN2 + store (lanes g<2) ----
    if (g < 2) {
        const float4 lb4 = *reinterpret_cast<const float4*>(&wl[O_L2B + k0]);
        const float4 g24 = *reinterpret_cast<const float4*>(&wl[O_G2 + k0]);
        const float4 b24 = *reinterpret_cast<const float4*>(&wl[O_B2 + k0]);
        float r20 = hh0 + acc[0] + lb4.x;
        float r21 = hh1 + acc[1] + lb4.y;
        float r22 = hh2 + acc[2] + lb4.z;
        float r23 = hh3 + acc[3] + lb4.w;
        float part = (r20 + r21) + (r22 + r23);
        float mean2 = (part + SWZ16(part)) * 0.125f;
        float e0 = r20 - mean2, e1 = r21 - mean2, e2 = r22 - mean2, e3 = r23 - mean2;
        float vp = (e0 * e0 + e1 * e1) + (e2 * e2 + e3 * e3);
        float rs2 = __builtin_amdgcn_rsqf((vp + SWZ16(vp)) * 0.125f + 1e-5f);
        float4 o;
        o.x = fmaf(e0 * rs2, g24.x, b24.x);
        o.y = fmaf(e1 * rs2, g24.y, b24.y);
        o.z = fmaf(e2 * rs2, g24.z, b24.z);
        o.w = fmaf(e3 * rs2, g24.w, b24.w);
        *reinterpret_cast<float4*>(out + (gtok + n) * 8 + k0) = o;
    }
}

extern "C" void kernel_launch(void* const* d_in, const int* in_sizes, int n_in,
                              void* d_out, int out_size, void* d_ws, size_t ws_size,
                              hipStream_t stream) {
    const float* x   = (const float*)d_in[0];
    const float* ipw = (const float*)d_in[1];
    const float* ipb = (const float*)d_in[2];
    const float* opw = (const float*)d_in[3];
    const float* opb = (const float*)d_in[4];
    const float* rxa = (const float*)d_in[5];
    const float* cw  = (const float*)d_in[6];
    const float* cb  = (const float*)d_in[7];
    const float* g1  = (const float*)d_in[8];
    const float* b1  = (const float*)d_in[9];
    const float* rxf = (const float*)d_in[10];
    const float* l1w = (const float*)d_in[11];
    const float* l1b = (const float*)d_in[12];
    const float* l2w = (const float*)d_in[13];
    const float* l2b = (const float*)d_in[14];
    const float* g2  = (const float*)d_in[15];
    const float* b2  = (const float*)d_in[16];
    float* out = (float*)d_out;

    const int tokens = 16384 * 8;               // 131072
    tbq_fused<<<dim3(tokens / 64), dim3(256), 0, stream>>>(
        x, ipw, ipb, opw, opb, rxa, cw, cb, g1, b1, rxf,
        l1w, l1b, l2w, l2b, g2, b2, out);
}

// Round 23
// 21.232 us; speedup vs baseline: 1.2367x; 1.2367x over previous
//
#include <hip/hip_runtime.h>

// TransformerBlockQuantum: B=16384, S=8, E=8, H=8 (dk=1), NW=8, FFN=512.
// R23 = R21 byte-for-byte EXCEPT __launch_bounds__(512,4): forces VGPR<=128
// -> 2 blocks/CU (LDS 35KB x2, 1024 thr) = 16 waves/CU = 4 waves/SIMD,
// keeping R21's 128-token/block pack amortization. Single-variable occupancy
// test (R22 confounded occupancy with pack amortization).
// Wave = 16 tokens = one 16x16 MFMA tile chain; all inter-matmul data packs
// IN-PLACE (D layout == next B operand layout).

typedef __fp16 half2v __attribute__((ext_vector_type(2)));
typedef __fp16 half4  __attribute__((ext_vector_type(4)));
typedef float  float4v __attribute__((ext_vector_type(4)));

#define SWZ16(v) __int_as_float(__builtin_amdgcn_ds_swizzle(__float_as_int(v), (16 << 10) | 0x1F))
#define SWZI_(v, dlit) __builtin_amdgcn_ds_swizzle((v), ((dlit) << 5) | 0x18)
#define GATHERJ8(dst, src)                                  \
    do {                                                    \
        dst[0] = SWZI_(src, 0); dst[1] = SWZI_(src, 1);     \
        dst[2] = SWZI_(src, 2); dst[3] = SWZI_(src, 3);     \
        dst[4] = SWZI_(src, 4); dst[5] = SWZI_(src, 5);     \
        dst[6] = SWZI_(src, 6); dst[7] = SWZI_(src, 7);     \
    } while (0)

// wl float offsets (16-float slots, zero-padded)
#define O_RXA 0
#define O_G1  16
#define O_B1  32
#define O_RXF 48
#define O_L2B 64
#define O_G2  80
#define O_B2  96

__global__ __launch_bounds__(512, 4) void tbq_fused(
    const float* __restrict__ x,
    const float* __restrict__ ipw, const float* __restrict__ ipb,
    const float* __restrict__ opw, const float* __restrict__ opb,
    const float* __restrict__ rxa,
    const float* __restrict__ cw,  const float* __restrict__ cb,
    const float* __restrict__ g1,  const float* __restrict__ b1,
    const float* __restrict__ rxf,
    const float* __restrict__ l1w, const float* __restrict__ l1b,
    const float* __restrict__ l2w, const float* __restrict__ l2b,
    const float* __restrict__ g2,  const float* __restrict__ b2,
    float* __restrict__ out)
{
    __shared__ half4 a1l[2048];                 // 16KB FFN lin1 frags
    __shared__ half4 a2l[2048];                 // 16KB FFN lin2 frags
    __shared__ half4 frontA[320];               // 2.5KB Wq,Wk,Wv,Wo,Wc frags
    __shared__ __align__(16) float wl[112];     // params, 16-float slots

    const int tid = threadIdx.x;
    const int l   = tid & 63;
    const int wv  = tid >> 6;                   // 0..7
    const int n   = l & 15;                     // token in tile
    const int g   = l >> 4;                     // row group (0..3)
    const int k0  = g * 4;
    const int gtok = blockIdx.x * 128 + wv * 16;

    // ---- x load early (B-operand source: x^T) ----
    float4 xw = make_float4(0.f, 0.f, 0.f, 0.f);
    if (g < 2) xw = *reinterpret_cast<const float4*>(x + (gtok + n) * 8 + k0);

    const half4 zh = {(__fp16)0.f, (__fp16)0.f, (__fp16)0.f, (__fp16)0.f};

    // ---- pack: front A-frags (bias at k==8), params, FFN frags ----
    if (tid < 320) {
        const int t = tid >> 6, ll = tid & 63;
        const int m = ll & 15, kk0 = (ll >> 4) * 4;
        half4 r = zh;
        if (m < 8) {
            const float* Wp = (t == 0) ? ipw : (t == 1) ? ipw + 64 :
                              (t == 2) ? ipw + 128 : (t == 3) ? opw : cw;
            const float* Bp = (t == 0) ? ipb : (t == 1) ? ipb + 8 :
                              (t == 2) ? ipb + 16 : (t == 3) ? opb : cb;
            #pragma unroll
            for (int j = 0; j < 4; ++j) {
                int k = kk0 + j;
                float v = (k < 8) ? Wp[m * 8 + k] : ((k == 8) ? Bp[m] : 0.f);
                r[j] = (__fp16)v;
            }
        }
        frontA[tid] = r;
    } else if (tid < 432) {
        const int p = (tid - 320) >> 4, i = (tid - 320) & 15;
        float v = 0.f;
        if (i < 8) {
            v = (p == 0) ? rxa[i] : (p == 1) ? g1[i] : (p == 2) ? b1[i] :
                (p == 3) ? rxf[i] : (p == 4) ? l2b[i] : (p == 5) ? g2[i] : b2[i];
        }
        wl[p * 16 + i] = v;
    }
    #pragma unroll 1
    for (int i = 0; i < 4; ++i) {
        const int u  = tid + i * 512;
        const int nf = u >> 6, ll = u & 63;
        const int mm = ll & 15, kk0 = (ll >> 4) * 4;
        half4 r1 = zh;
        if (ll < 32) {
            float4 w = *reinterpret_cast<const float4*>(l1w + (nf * 16 + mm) * 8 + kk0);
            half2v c0 = __builtin_amdgcn_cvt_pkrtz(w.x, w.y);
            half2v c1 = __builtin_amdgcn_cvt_pkrtz(w.z, w.w);
            r1.x = c0.x; r1.y = c0.y; r1.z = c1.x; r1.w = c1.y;
        } else if (ll < 48) {
            r1.x = (__fp16)l1b[nf * 16 + mm];
        }
        a1l[u] = r1;
        half4 r2 = zh;
        if (mm < 8) {
            float4 w = *reinterpret_cast<const float4*>(l2w + mm * 512 + nf * 16 + kk0);
            half2v c0 = __builtin_amdgcn_cvt_pkrtz(w.x, w.y);
            half2v c1 = __builtin_amdgcn_cvt_pkrtz(w.z, w.w);
            r2.x = c0.x; r2.y = c0.y; r2.z = c1.x; r2.w = c1.y;
        }
        a2l[u] = r2;
    }
    __syncthreads();

    // ---- B-fragment of x (k=embed, n=token); bias row k==8 = 1 ----
    half4 bx = zh;
    if (g < 2) {
        half2v p0 = __builtin_amdgcn_cvt_pkrtz(xw.x, xw.y);
        half2v p1 = __builtin_amdgcn_cvt_pkrtz(xw.z, xw.w);
        bx.x = p0.x; bx.y = p0.y; bx.z = p1.x; bx.w = p1.y;
    } else if (g == 2) bx.x = (__fp16)1.f;

    half4 Aq = frontA[l],       Ak = frontA[64 + l], Av = frontA[128 + l];
    half4 Ao = frontA[192 + l], Ac = frontA[256 + l];

    const float4v zero4 = {0.f, 0.f, 0.f, 0.f};
    float4v qf = __builtin_amdgcn_mfma_f32_16x16x16f16(Aq, bx, zero4, 0, 0, 0);
    float4v kf = __builtin_amdgcn_mfma_f32_16x16x16f16(Ak, bx, zero4, 0, 0, 0);
    float4v vf = __builtin_amdgcn_mfma_f32_16x16x16f16(Av, bx, zero4, 0, 0, 0);

    // ---- attention: lane holds heads 4g+r of token n; j-gather in batch ----
    float orow[4];
    #pragma unroll
    for (int r = 0; r < 4; ++r) {
        half2v pk = __builtin_amdgcn_cvt_pkrtz(kf[r], vf[r]);
        int kvp = __builtin_bit_cast(int, pk);
        int kvg[8];
        GATHERJ8(kvg, kvp);
        const float qh2 = qf[r] * 1.44269504f;
        float sum = 0.f, ov = 0.f;
        #pragma unroll
        for (int j = 0; j < 8; ++j) {
            half2v kv = __builtin_bit_cast(half2v, kvg[j]);
            float p = exp2f(qh2 * (float)kv.x);
            sum += p;
            ov = fmaf(p, (float)kv.y, ov);
        }
        orow[r] = ov * __builtin_amdgcn_rcpf(sum);
    }

    // ---- out_proj: orow packs IN-PLACE to B ----
    half4 bo = zh;
    if (g < 2) {
        half2v p0 = __builtin_amdgcn_cvt_pkrtz(orow[0], orow[1]);
        half2v p1 = __builtin_amdgcn_cvt_pkrtz(orow[2], orow[3]);
        bo.x = p0.x; bo.y = p0.y; bo.z = p1.x; bo.w = p1.y;
    } else if (g == 2) bo.x = (__fp16)1.f;
    float4v aof = __builtin_amdgcn_mfma_f32_16x16x16f16(Ao, bo, zero4, 0, 0, 0);

    // ---- quantum ring: c on own 4 wires, xor-16 exchange, full z ----
    const float4 rxa4 = *reinterpret_cast<const float4*>(&wl[O_RXA + k0]);
    float cx0 = __cosf(aof[0] + rxa4.x), cx1 = __cosf(aof[1] + rxa4.y);
    float cx2 = __cosf(aof[2] + rxa4.z), cx3 = __cosf(aof[3] + rxa4.w);
    float ct0 = SWZ16(cx0), ct1 = SWZ16(cx1), ct2 = SWZ16(cx2), ct3 = SWZ16(cx3);
    const bool sel = (g == 0);
    float cc[8];
    cc[0] = sel ? cx0 : ct0; cc[1] = sel ? cx1 : ct1;
    cc[2] = sel ? cx2 : ct2; cc[3] = sel ? cx3 : ct3;
    cc[4] = sel ? ct0 : cx0; cc[5] = sel ? ct1 : cx1;
    cc[6] = sel ? ct2 : cx2; cc[7] = sel ? ct3 : cx3;
    float z8[8];
    {
        float run = cc[0];
        #pragma unroll
        for (int w = 1; w < 8; ++w) { run *= cc[w]; z8[w] = run; }
        float s17 = cc[1];
        #pragma unroll
        for (int w = 2; w < 8; ++w) s17 *= cc[w];
        z8[0] = s17;
    }

    // ---- combine1: z packs in-place (g picks own half) ----
    float zs0 = sel ? z8[0] : z8[4], zs1 = sel ? z8[1] : z8[5];
    float zs2 = sel ? z8[2] : z8[6], zs3 = sel ? z8[3] : z8[7];
    half4 bz1 = zh;
    if (g < 2) {
        half2v p0 = __builtin_amdgcn_cvt_pkrtz(zs0, zs1);
        half2v p1 = __builtin_amdgcn_cvt_pkrtz(zs2, zs3);
        bz1.x = p0.x; bz1.y = p0.y; bz1.z = p1.x; bz1.w = p1.y;
    } else if (g == 2) bz1.x = (__fp16)1.f;
    float4v qo = __builtin_amdgcn_mfma_f32_16x16x16f16(Ac, bz1, zero4, 0, 0, 0);
    float4v saqf = aof + qo;

    // ---- combine2: saq packs in-place ----
    half4 bs = zh;
    if (g < 2) {
        half2v p0 = __builtin_amdgcn_cvt_pkrtz(saqf[0], saqf[1]);
        half2v p1 = __builtin_amdgcn_cvt_pkrtz(saqf[2], saqf[3]);
        bs.x = p0.x; bs.y = p0.y; bs.z = p1.x; bs.w = p1.y;
    } else if (g == 2) bs.x = (__fp16)1.f;
    float4v atf = __builtin_amdgcn_mfma_f32_16x16x16f16(Ac, bs, zero4, 0, 0, 0);

    // ---- LayerNorm1 (xor-16 reductions across g=0/1) ----
    float r10 = xw.x + atf[0], r11 = xw.y + atf[1];
    float r12 = xw.z + atf[2], r13 = xw.w + atf[3];
    float s4 = (r10 + r11) + (r12 + r13);
    float mean = (s4 + SWZ16(s4)) * 0.125f;
    float dv0 = r10 - mean, dv1 = r11 - mean, dv2 = r12 - mean, dv3 = r13 - mean;
    float vq = (dv0 * dv0 + dv1 * dv1) + (dv2 * dv2 + dv3 * dv3);
    float var = (vq + SWZ16(vq)) * 0.125f;
    float rs = __builtin_amdgcn_rsqf(var + 1e-5f);
    const float4 g14 = *reinterpret_cast<const float4*>(&wl[O_G1 + k0]);
    const float4 b14 = *reinterpret_cast<const float4*>(&wl[O_B1 + k0]);
    float hh0 = fmaf(dv0 * rs, g14.x, b14.x);
    float hh1 = fmaf(dv1 * rs, g14.y, b14.y);
    float hh2 = fmaf(dv2 * rs, g14.z, b14.z);
    float hh3 = fmaf(dv3 * rs, g14.w, b14.w);

    // ---- zf packs in-place into FFN B-fragment ----
    const float4 rxf4 = *reinterpret_cast<const float4*>(&wl[O_RXF + k0]);
    half4 bz = zh;
    if (g < 2) {
        half2v p0 = __builtin_amdgcn_cvt_pkrtz(__cosf(hh0 + rxf4.x), __cosf(hh1 + rxf4.y));
        half2v p1 = __builtin_amdgcn_cvt_pkrtz(__cosf(hh2 + rxf4.z), __cosf(hh3 + rxf4.w));
        bz.x = p0.x; bz.y = p0.y; bz.z = p1.x; bz.w = p1.y;
    } else if (g == 2) bz.x = (__fp16)1.f;

    // ---- FFN: one tile, 32 chunks ----
    float4v acc = zero4;
    #pragma unroll 4
    for (int nf = 0; nf < 32; ++nf) {
        half4 a1f = a1l[nf * 64 + l];
        half4 a2f = a2l[nf * 64 + l];
        float4v d = __builtin_amdgcn_mfma_f32_16x16x16f16(a1f, bz, zero4, 0, 0, 0);
        half2v p0 = __builtin_amdgcn_cvt_pkrtz(d[0], d[1]);
        half2v p1 = __builtin_amdgcn_cvt_pkrtz(d[2], d[3]);
        half4 bu; bu.x = p0.x; bu.y = p0.y; bu.z = p1.x; bu.w = p1.y;
        bu = __builtin_elementwise_max(bu, zh);
        acc = __builtin_amdgcn_mfma_f32_16x16x16f16(a2f, bu, acc, 0, 0, 0);
    }

    // ---- residual + LN2 + store (lanes g<2) ----
    if (g < 2) {
        const float4 lb4 = *reinterpret_cast<const float4*>(&wl[O_L2B + k0]);
        const float4 g24 = *reinterpret_cast<const float4*>(&wl[O_G2 + k0]);
        const float4 b24 = *reinterpret_cast<const float4*>(&wl[O_B2 + k0]);
        float r20 = hh0 + acc[0] + lb4.x;
        float r21 = hh1 + acc[1] + lb4.y;
        float r22 = hh2 + acc[2] + lb4.z;
        float r23 = hh3 + acc[3] + lb4.w;
        float part = (r20 + r21) + (r22 + r23);
        float mean2 = (part + SWZ16(part)) * 0.125f;
        float e0 = r20 - mean2, e1 = r21 - mean2, e2 = r22 - mean2, e3 = r23 - mean2;
        float vp = (e0 * e0 + e1 * e1) + (e2 * e2 + e3 * e3);
        float rs2 = __builtin_amdgcn_rsqf((vp + SWZ16(vp)) * 0.125f + 1e-5f);
        float4 o;
        o.x = fmaf(e0 * rs2, g24.x, b24.x);
        o.y = fmaf(e1 * rs2, g24.y, b24.y);
        o.z = fmaf(e2 * rs2, g24.z, b24.z);
        o.w = fmaf(e3 * rs2, g24.w, b24.w);
        *reinterpret_cast<float4*>(out + (gtok + n) * 8 + k0) = o;
    }
}

extern "C" void kernel_launch(void* const* d_in, const int* in_sizes, int n_in,
                              void* d_out, int out_size, void* d_ws, size_t ws_size,
                              hipStream_t stream) {
    const float* x   = (const float*)d_in[0];
    const float* ipw = (const float*)d_in[1];
    const float* ipb = (const float*)d_in[2];
    const float* opw = (const float*)d_in[3];
    const float* opb = (const float*)d_in[4];
    const float* rxa = (const float*)d_in[5];
    const float* cw  = (const float*)d_in[6];
    const float* cb  = (const float*)d_in[7];
    const float* g1  = (const float*)d_in[8];
    const float* b1  = (const float*)d_in[9];
    const float* rxf = (const float*)d_in[10];
    const float* l1w = (const float*)d_in[11];
    const float* l1b = (const float*)d_in[12];
    const float* l2w = (const float*)d_in[13];
    const float* l2b = (const float*)d_in[14];
    const float* g2  = (const float*)d_in[15];
    const float* b2  = (const float*)d_in[16];
    float* out = (float*)d_out;

    const int tokens = 16384 * 8;               // 131072
    tbq_fused<<<dim3(tokens / 128), dim3(512), 0, stream>>>(
        x, ipw, ipb, opw, opb, rxa, cw, cb, g1, b1, rxf,
        l1w, l1b, l2w, l2b, g2, b2, out);
}

// Round 24
// 20.564 us; speedup vs baseline: 1.2769x; 1.0325x over previous
//
#include <hip/hip_runtime.h>

// TransformerBlockQuantum: B=16384, S=8, E=8, H=8 (dk=1), NW=8, FFN=512.
// R24 = R21/R23 MFMA-front pipeline with TWO tile-chains per wave:
// block = 512 thr = 8 waves = 256 tokens (pack amortization 2x R21);
// wave = 2 independent 16-token chains interleaved (front MFMA ILP, FFN
// 4 MFMA/iter). launch_bounds(512,4): VGPR<=128 -> 2 blocks/CU (LDS 70KB)
// = 4 waves/SIMD. Grid 512.

typedef __fp16 half2v __attribute__((ext_vector_type(2)));
typedef __fp16 half4  __attribute__((ext_vector_type(4)));
typedef float  float4v __attribute__((ext_vector_type(4)));

#define SWZ16(v) __int_as_float(__builtin_amdgcn_ds_swizzle(__float_as_int(v), (16 << 10) | 0x1F))
#define SWZI_(v, dlit) __builtin_amdgcn_ds_swizzle((v), ((dlit) << 5) | 0x18)
#define GATHERJ8(dst, src)                                  \
    do {                                                    \
        dst[0] = SWZI_(src, 0); dst[1] = SWZI_(src, 1);     \
        dst[2] = SWZI_(src, 2); dst[3] = SWZI_(src, 3);     \
        dst[4] = SWZI_(src, 4); dst[5] = SWZI_(src, 5);     \
        dst[6] = SWZI_(src, 6); dst[7] = SWZI_(src, 7);     \
    } while (0)

// wl float offsets (16-float slots, zero-padded)
#define O_RXA 0
#define O_G1  16
#define O_B1  32
#define O_RXF 48
#define O_L2B 64
#define O_G2  80
#define O_B2  96

__global__ __launch_bounds__(512, 4) void tbq_fused(
    const float* __restrict__ x,
    const float* __restrict__ ipw, const float* __restrict__ ipb,
    const float* __restrict__ opw, const float* __restrict__ opb,
    const float* __restrict__ rxa,
    const float* __restrict__ cw,  const float* __restrict__ cb,
    const float* __restrict__ g1,  const float* __restrict__ b1,
    const float* __restrict__ rxf,
    const float* __restrict__ l1w, const float* __restrict__ l1b,
    const float* __restrict__ l2w, const float* __restrict__ l2b,
    const float* __restrict__ g2,  const float* __restrict__ b2,
    float* __restrict__ out)
{
    __shared__ half4 a1l[2048];                 // 16KB FFN lin1 frags
    __shared__ half4 a2l[2048];                 // 16KB FFN lin2 frags
    __shared__ half4 frontA[320];               // 2.5KB Wq,Wk,Wv,Wo,Wc frags
    __shared__ __align__(16) float wl[112];     // params, 16-float slots

    const int tid = threadIdx.x;
    const int l   = tid & 63;
    const int wv  = tid >> 6;                   // 0..7
    const int n   = l & 15;                     // token in tile
    const int g   = l >> 4;                     // row group (0..3)
    const int k0  = g * 4;
    const int base0 = blockIdx.x * 256 + wv * 32;   // wave's 32 tokens

    // ---- x loads early (both chains) ----
    float4 xw[2];
    xw[0] = make_float4(0.f, 0.f, 0.f, 0.f); xw[1] = xw[0];
    if (g < 2) {
        xw[0] = *reinterpret_cast<const float4*>(x + (base0 + n) * 8 + k0);
        xw[1] = *reinterpret_cast<const float4*>(x + (base0 + 16 + n) * 8 + k0);
    }

    const half4 zh = {(__fp16)0.f, (__fp16)0.f, (__fp16)0.f, (__fp16)0.f};

    // ---- pack: front A-frags (bias at k==8), params, FFN frags ----
    if (tid < 320) {
        const int t = tid >> 6, ll = tid & 63;
        const int m = ll & 15, kk0 = (ll >> 4) * 4;
        half4 r = zh;
        if (m < 8) {
            const float* Wp = (t == 0) ? ipw : (t == 1) ? ipw + 64 :
                              (t == 2) ? ipw + 128 : (t == 3) ? opw : cw;
            const float* Bp = (t == 0) ? ipb : (t == 1) ? ipb + 8 :
                              (t == 2) ? ipb + 16 : (t == 3) ? opb : cb;
            #pragma unroll
            for (int j = 0; j < 4; ++j) {
                int k = kk0 + j;
                float v = (k < 8) ? Wp[m * 8 + k] : ((k == 8) ? Bp[m] : 0.f);
                r[j] = (__fp16)v;
            }
        }
        frontA[tid] = r;
    } else if (tid < 432) {
        const int p = (tid - 320) >> 4, i = (tid - 320) & 15;
        float v = 0.f;
        if (i < 8) {
            v = (p == 0) ? rxa[i] : (p == 1) ? g1[i] : (p == 2) ? b1[i] :
                (p == 3) ? rxf[i] : (p == 4) ? l2b[i] : (p == 5) ? g2[i] : b2[i];
        }
        wl[p * 16 + i] = v;
    }
    #pragma unroll 1
    for (int i = 0; i < 4; ++i) {
        const int u  = tid + i * 512;
        const int nf = u >> 6, ll = u & 63;
        const int mm = ll & 15, kk0 = (ll >> 4) * 4;
        half4 r1 = zh;
        if (ll < 32) {
            float4 w = *reinterpret_cast<const float4*>(l1w + (nf * 16 + mm) * 8 + kk0);
            half2v c0 = __builtin_amdgcn_cvt_pkrtz(w.x, w.y);
            half2v c1 = __builtin_amdgcn_cvt_pkrtz(w.z, w.w);
            r1.x = c0.x; r1.y = c0.y; r1.z = c1.x; r1.w = c1.y;
        } else if (ll < 48) {
            r1.x = (__fp16)l1b[nf * 16 + mm];
        }
        a1l[u] = r1;
        half4 r2 = zh;
        if (mm < 8) {
            float4 w = *reinterpret_cast<const float4*>(l2w + mm * 512 + nf * 16 + kk0);
            half2v c0 = __builtin_amdgcn_cvt_pkrtz(w.x, w.y);
            half2v c1 = __builtin_amdgcn_cvt_pkrtz(w.z, w.w);
            r2.x = c0.x; r2.y = c0.y; r2.z = c1.x; r2.w = c1.y;
        }
        a2l[u] = r2;
    }
    __syncthreads();

    half4 Aq = frontA[l],       Ak = frontA[64 + l], Av = frontA[128 + l];
    half4 Ao = frontA[192 + l], Ac = frontA[256 + l];
    const float4v zero4 = {0.f, 0.f, 0.f, 0.f};

    // ---- B-fragments of x; QKV MFMAs for both chains (6-way ILP) ----
    half4 bx[2]; bx[0] = zh; bx[1] = zh;
    #pragma unroll
    for (int t = 0; t < 2; ++t) {
        if (g < 2) {
            half2v p0 = __builtin_amdgcn_cvt_pkrtz(xw[t].x, xw[t].y);
            half2v p1 = __builtin_amdgcn_cvt_pkrtz(xw[t].z, xw[t].w);
            bx[t].x = p0.x; bx[t].y = p0.y; bx[t].z = p1.x; bx[t].w = p1.y;
        } else if (g == 2) bx[t].x = (__fp16)1.f;
    }

    float4v qf[2], kf[2], vf[2];
    #pragma unroll
    for (int t = 0; t < 2; ++t) {
        qf[t] = __builtin_amdgcn_mfma_f32_16x16x16f16(Aq, bx[t], zero4, 0, 0, 0);
        kf[t] = __builtin_amdgcn_mfma_f32_16x16x16f16(Ak, bx[t], zero4, 0, 0, 0);
        vf[t] = __builtin_amdgcn_mfma_f32_16x16x16f16(Av, bx[t], zero4, 0, 0, 0);
    }

    // ---- per-chain: attention -> out_proj -> ring -> combines -> LN1 -> zf ----
    half4 bzf[2]; bzf[0] = zh; bzf[1] = zh;
    float hhv[2][4];
    const bool sel = (g == 0);
    const float4 rxa4 = *reinterpret_cast<const float4*>(&wl[O_RXA + k0]);
    const float4 g14  = *reinterpret_cast<const float4*>(&wl[O_G1 + k0]);
    const float4 b14  = *reinterpret_cast<const float4*>(&wl[O_B1 + k0]);
    const float4 rxf4 = *reinterpret_cast<const float4*>(&wl[O_RXF + k0]);

    #pragma unroll
    for (int t = 0; t < 2; ++t) {
        // attention
        float orow[4];
        #pragma unroll
        for (int r = 0; r < 4; ++r) {
            half2v pk = __builtin_amdgcn_cvt_pkrtz(kf[t][r], vf[t][r]);
            int kvp = __builtin_bit_cast(int, pk);
            int kvg[8];
            GATHERJ8(kvg, kvp);
            const float qh2 = qf[t][r] * 1.44269504f;
            float sum = 0.f, ov = 0.f;
            #pragma unroll
            for (int j = 0; j < 8; ++j) {
                half2v kv = __builtin_bit_cast(half2v, kvg[j]);
                float p = exp2f(qh2 * (float)kv.x);
                sum += p;
                ov = fmaf(p, (float)kv.y, ov);
            }
            orow[r] = ov * __builtin_amdgcn_rcpf(sum);
        }

        // out_proj
        half4 bo = zh;
        if (g < 2) {
            half2v p0 = __builtin_amdgcn_cvt_pkrtz(orow[0], orow[1]);
            half2v p1 = __builtin_amdgcn_cvt_pkrtz(orow[2], orow[3]);
            bo.x = p0.x; bo.y = p0.y; bo.z = p1.x; bo.w = p1.y;
        } else if (g == 2) bo.x = (__fp16)1.f;
        float4v aof = __builtin_amdgcn_mfma_f32_16x16x16f16(Ao, bo, zero4, 0, 0, 0);

        // quantum ring
        float cx0 = __cosf(aof[0] + rxa4.x), cx1 = __cosf(aof[1] + rxa4.y);
        float cx2 = __cosf(aof[2] + rxa4.z), cx3 = __cosf(aof[3] + rxa4.w);
        float ct0 = SWZ16(cx0), ct1 = SWZ16(cx1), ct2 = SWZ16(cx2), ct3 = SWZ16(cx3);
        float cc[8];
        cc[0] = sel ? cx0 : ct0; cc[1] = sel ? cx1 : ct1;
        cc[2] = sel ? cx2 : ct2; cc[3] = sel ? cx3 : ct3;
        cc[4] = sel ? ct0 : cx0; cc[5] = sel ? ct1 : cx1;
        cc[6] = sel ? ct2 : cx2; cc[7] = sel ? ct3 : cx3;
        float z8[8];
        {
            float run = cc[0];
            #pragma unroll
            for (int w = 1; w < 8; ++w) { run *= cc[w]; z8[w] = run; }
            float s17 = cc[1];
            #pragma unroll
            for (int w = 2; w < 8; ++w) s17 *= cc[w];
            z8[0] = s17;
        }

        // combine1
        float zs0 = sel ? z8[0] : z8[4], zs1 = sel ? z8[1] : z8[5];
        float zs2 = sel ? z8[2] : z8[6], zs3 = sel ? z8[3] : z8[7];
        half4 bz1 = zh;
        if (g < 2) {
            half2v p0 = __builtin_amdgcn_cvt_pkrtz(zs0, zs1);
            half2v p1 = __builtin_amdgcn_cvt_pkrtz(zs2, zs3);
            bz1.x = p0.x; bz1.y = p0.y; bz1.z = p1.x; bz1.w = p1.y;
        } else if (g == 2) bz1.x = (__fp16)1.f;
        float4v qo = __builtin_amdgcn_mfma_f32_16x16x16f16(Ac, bz1, zero4, 0, 0, 0);
        float4v saqf = aof + qo;

        // combine2
        half4 bs = zh;
        if (g < 2) {
            half2v p0 = __builtin_amdgcn_cvt_pkrtz(saqf[0], saqf[1]);
            half2v p1 = __builtin_amdgcn_cvt_pkrtz(saqf[2], saqf[3]);
            bs.x = p0.x; bs.y = p0.y; bs.z = p1.x; bs.w = p1.y;
        } else if (g == 2) bs.x = (__fp16)1.f;
        float4v atf = __builtin_amdgcn_mfma_f32_16x16x16f16(Ac, bs, zero4, 0, 0, 0);

        // LayerNorm1
        float r10 = xw[t].x + atf[0], r11 = xw[t].y + atf[1];
        float r12 = xw[t].z + atf[2], r13 = xw[t].w + atf[3];
        float s4 = (r10 + r11) + (r12 + r13);
        float mean = (s4 + SWZ16(s4)) * 0.125f;
        float dv0 = r10 - mean, dv1 = r11 - mean, dv2 = r12 - mean, dv3 = r13 - mean;
        float vq = (dv0 * dv0 + dv1 * dv1) + (dv2 * dv2 + dv3 * dv3);
        float var = (vq + SWZ16(vq)) * 0.125f;
        float rs = __builtin_amdgcn_rsqf(var + 1e-5f);
        hhv[t][0] = fmaf(dv0 * rs, g14.x, b14.x);
        hhv[t][1] = fmaf(dv1 * rs, g14.y, b14.y);
        hhv[t][2] = fmaf(dv2 * rs, g14.z, b14.z);
        hhv[t][3] = fmaf(dv3 * rs, g14.w, b14.w);

        // zf -> FFN B-fragment
        if (g < 2) {
            half2v p0 = __builtin_amdgcn_cvt_pkrtz(__cosf(hhv[t][0] + rxf4.x),
                                                   __cosf(hhv[t][1] + rxf4.y));
            half2v p1 = __builtin_amdgcn_cvt_pkrtz(__cosf(hhv[t][2] + rxf4.z),
                                                   __cosf(hhv[t][3] + rxf4.w));
            bzf[t].x = p0.x; bzf[t].y = p0.y; bzf[t].z = p1.x; bzf[t].w = p1.y;
        } else if (g == 2) bzf[t].x = (__fp16)1.f;
    }

    // ---- FFN: 2 tiles, 4 MFMA chains/iter ----
    float4v acc0 = zero4, acc1 = zero4;
    #pragma unroll 2
    for (int nf = 0; nf < 32; ++nf) {
        half4 a1f = a1l[nf * 64 + l];
        half4 a2f = a2l[nf * 64 + l];
        float4v d0 = __builtin_amdgcn_mfma_f32_16x16x16f16(a1f, bzf[0], zero4, 0, 0, 0);
        float4v d1 = __builtin_amdgcn_mfma_f32_16x16x16f16(a1f, bzf[1], zero4, 0, 0, 0);
        half4 bu0, bu1;
        {
            half2v p0 = __builtin_amdgcn_cvt_pkrtz(d0[0], d0[1]);
            half2v p1 = __builtin_amdgcn_cvt_pkrtz(d0[2], d0[3]);
            bu0.x = p0.x; bu0.y = p0.y; bu0.z = p1.x; bu0.w = p1.y;
            p0 = __builtin_amdgcn_cvt_pkrtz(d1[0], d1[1]);
            p1 = __builtin_amdgcn_cvt_pkrtz(d1[2], d1[3]);
            bu1.x = p0.x; bu1.y = p0.y; bu1.z = p1.x; bu1.w = p1.y;
        }
        bu0 = __builtin_elementwise_max(bu0, zh);
        bu1 = __builtin_elementwise_max(bu1, zh);
        acc0 = __builtin_amdgcn_mfma_f32_16x16x16f16(a2f, bu0, acc0, 0, 0, 0);
        acc1 = __builtin_amdgcn_mfma_f32_16x16x16f16(a2f, bu1, acc1, 0, 0, 0);
    }

    // ---- residual + LN2 + store (lanes g<2, both chains) ----
    if (g < 2) {
        const float4 lb4 = *reinterpret_cast<const float4*>(&wl[O_L2B + k0]);
        const float4 g24 = *reinterpret_cast<const float4*>(&wl[O_G2 + k0]);
        const float4 b24 = *reinterpret_cast<const float4*>(&wl[O_B2 + k0]);

        #pragma unroll
        for (int t = 0; t < 2; ++t) {
            float4v acc = t ? acc1 : acc0;
            float r20 = hhv[t][0] + acc[0] + lb4.x;
            float r21 = hhv[t][1] + acc[1] + lb4.y;
            float r22 = hhv[t][2] + acc[2] + lb4.z;
            float r23 = hhv[t][3] + acc[3] + lb4.w;
            float part = (r20 + r21) + (r22 + r23);
            float mean2 = (part + SWZ16(part)) * 0.125f;
            float e0 = r20 - mean2, e1 = r21 - mean2, e2 = r22 - mean2, e3 = r23 - mean2;
            float vp = (e0 * e0 + e1 * e1) + (e2 * e2 + e3 * e3);
            float rs2 = __builtin_amdgcn_rsqf((vp + SWZ16(vp)) * 0.125f + 1e-5f);
            float4 o;
            o.x = fmaf(e0 * rs2, g24.x, b24.x);
            o.y = fmaf(e1 * rs2, g24.y, b24.y);
            o.z = fmaf(e2 * rs2, g24.z, b24.z);
            o.w = fmaf(e3 * rs2, g24.w, b24.w);
            *reinterpret_cast<float4*>(out + (base0 + t * 16 + n) * 8 + k0) = o;
        }
    }
}

extern "C" void kernel_launch(void* const* d_in, const int* in_sizes, int n_in,
                              void* d_out, int out_size, void* d_ws, size_t ws_size,
                              hipStream_t stream) {
    const float* x   = (const float*)d_in[0];
    const float* ipw = (const float*)d_in[1];
    const float* ipb = (const float*)d_in[2];
    const float* opw = (const float*)d_in[3];
    const float* opb = (const float*)d_in[4];
    const float* rxa = (const float*)d_in[5];
    const float* cw  = (const float*)d_in[6];
    const float* cb  = (const float*)d_in[7];
    const float* g1  = (const float*)d_in[8];
    const float* b1  = (const float*)d_in[9];
    const float* rxf = (const float*)d_in[10];
    const float* l1w = (const float*)d_in[11];
    const float* l1b = (const float*)d_in[12];
    const float* l2w = (const float*)d_in[13];
    const float* l2b = (const float*)d_in[14];
    const float* g2  = (const float*)d_in[15];
    const float* b2  = (const float*)d_in[16];
    float* out = (float*)d_out;

    const int tokens = 16384 * 8;               // 131072
    tbq_fused<<<dim3(tokens / 256), dim3(512), 0, stream>>>(
        x, ipw, ipb, opw, opb, rxa, cw, cb, g1, b1, rxf,
        l1w, l1b, l2w, l2b, g2, b2, out);
}